// Round 1
// baseline (2124.174 us; speedup 1.0000x reference)
//
#include <hip/hip_runtime.h>

__device__ __forceinline__ float lrelu(float v, float s) { return v >= 0.f ? v : s * v; }

__device__ __forceinline__ float wave_sum64(float v) {
#pragma unroll
  for (int m = 1; m < 64; m <<= 1) v += __shfl_xor(v, m, 64);
  return v;
}
__device__ __forceinline__ float wave_max64(float v) {
#pragma unroll
  for (int m = 1; m < 64; m <<= 1) v = fmaxf(v, __shfl_xor(v, m, 64));
  return v;
}

// --- detect whether edge_index arrived as int64 or int32 ---
__global__ void k_detect(const void* __restrict__ ei, int N, int* __restrict__ flag) {
  __shared__ int bad;
  if (threadIdx.x == 0) bad = 0;
  __syncthreads();
  const long long* p = (const long long*)ei;
  int my = 0;
  for (int i = threadIdx.x; i < 1024; i += blockDim.x) {
    long long v = p[i];
    if (v < 0 || v >= (long long)N) my = 1;
  }
  if (my) atomicExch(&bad, 1);
  __syncthreads();
  if (threadIdx.x == 0) *flag = bad ? 0 : 1;  // 1 => int64
}

// --- per-node attention logits al_src/al_dst [N,8]; al = x . (W_h a_h) ---
__global__ void k_alpha(const float* __restrict__ x, const float* __restrict__ Wc,
                        const float* __restrict__ a_src, const float* __restrict__ a_dst,
                        float* __restrict__ als, float* __restrict__ ald, int N) {
  __shared__ float vs[128], vd[128];
  for (int t = threadIdx.x; t < 256; t += blockDim.x) {
    int h = (t & 127) >> 4, d = t & 15;
    const float* wrow = Wc + h * 256 + d * 16;
    const float* av = (t < 128 ? a_src : a_dst) + h * 16;
    float s = 0.f;
#pragma unroll
    for (int f = 0; f < 16; ++f) s += wrow[f] * av[f];
    if (t < 128) vs[h * 16 + d] = s; else vd[h * 16 + d] = s;
  }
  __syncthreads();
  for (int n = blockIdx.x * blockDim.x + threadIdx.x; n < N; n += gridDim.x * blockDim.x) {
    float xv[16];
    const float4* xr = (const float4*)(x + (size_t)n * 16);
#pragma unroll
    for (int q = 0; q < 4; ++q) {
      float4 t4 = xr[q];
      xv[q * 4 + 0] = t4.x; xv[q * 4 + 1] = t4.y; xv[q * 4 + 2] = t4.z; xv[q * 4 + 3] = t4.w;
    }
    float rs[8], rd[8];
#pragma unroll
    for (int h = 0; h < 8; ++h) {
      float s1 = 0.f, s2 = 0.f;
#pragma unroll
      for (int d = 0; d < 16; ++d) { s1 += xv[d] * vs[h * 16 + d]; s2 += xv[d] * vd[h * 16 + d]; }
      rs[h] = s1; rd[h] = s2;
    }
    float4* po = (float4*)(als + (size_t)n * 8);
    po[0] = make_float4(rs[0], rs[1], rs[2], rs[3]);
    po[1] = make_float4(rs[4], rs[5], rs[6], rs[7]);
    float4* pd = (float4*)(ald + (size_t)n * 8);
    pd[0] = make_float4(rd[0], rd[1], rd[2], rd[3]);
    pd[1] = make_float4(rd[4], rd[5], rd[6], rd[7]);
  }
}

// --- edge scatter: agg[dst][h][d] += w*x[src][d]; denom[dst][h] += w.
// One wave per edge; lane l handles head h=l>>3, feature pair dp=l&7.
__global__ void k_edge(const void* __restrict__ ei, const int* __restrict__ flag,
                       const float* __restrict__ x,
                       const float* __restrict__ als, const float* __restrict__ ald,
                       float* __restrict__ agg, float* __restrict__ denom, int E, int N) {
  const int is64 = *flag;
  const long long EE = (long long)E + N;
  const int lane = threadIdx.x & 63;
  const int h = lane >> 3, dp = lane & 7;
  long long w0 = ((long long)blockIdx.x * blockDim.x + threadIdx.x) >> 6;
  long long nw = ((long long)gridDim.x * blockDim.x) >> 6;
  for (long long e = w0; e < EE; e += nw) {
    int s, d;
    if (e < E) {
      if (is64) { s = (int)((const long long*)ei)[e]; d = (int)((const long long*)ei)[E + e]; }
      else      { s = ((const int*)ei)[e];            d = ((const int*)ei)[E + e]; }
    } else { s = d = (int)(e - E); }
    float w = __expf(lrelu(als[(size_t)s * 8 + h] + ald[(size_t)d * 8 + h], 0.2f));
    float2 xv = ((const float2*)(x + (size_t)s * 16))[dp];
    float* ag = agg + (size_t)d * 128 + h * 16 + dp * 2;
    atomicAdd(ag, xv.x * w);
    atomicAdd(ag + 1, xv.y * w);
    if (dp == 0) atomicAdd(denom + (size_t)d * 8 + h, w);
  }
}

// --- per-node dense chain. One wave per node; lane owns channels (lane, lane+64).
__global__ __launch_bounds__(256) void k_nodefc(
    const float* __restrict__ agg, const float* __restrict__ denom,
    const float* __restrict__ Wc, const float* __restrict__ b_conv,
    const float* __restrict__ fcW, const float* __restrict__ fcb,
    const float* __restrict__ lng, const float* __restrict__ lnb,
    float* __restrict__ out, float* __restrict__ colsum, int N) {
  __shared__ float4 fw[4096];      // fc_W rows, XOR-swizzled float4 chunks (64KB)
  __shared__ float W2t[2048];      // W_conv as [d][h*16+f] (8KB)
  __shared__ __align__(16) float4 xls4[4][32];  // per-wave 128-float buffer
  const float4* fwg = (const float4*)fcW;
  for (int i = threadIdx.x; i < 4096; i += blockDim.x) {
    int c = i >> 5, j = i & 31;
    fw[(c << 5) | (j ^ (c & 31))] = fwg[i];
  }
  for (int i = threadIdx.x; i < 2048; i += blockDim.x) {
    int h = i >> 8, d = (i >> 4) & 15, f = i & 15;
    W2t[d * 128 + h * 16 + f] = Wc[i];
  }
  __syncthreads();
  const int wid = threadIdx.x >> 6, lane = threadIdx.x & 63;
  const int c0 = lane, c1 = lane + 64;
  const int h0 = lane >> 4, h1 = h0 + 4;
  const int ca = lane & 31;
  float* myx = (float*)xls4[wid];
  const float4* myx4 = xls4[wid];
  const int b0 = c0 << 5, b1 = c1 << 5;
  const float fb0 = fcb[c0], fb1 = fcb[c1];
  const float bc0 = b_conv[c0], bc1 = b_conv[c1];
  const float g0 = lng[c0], g1 = lng[c1];
  const float be0 = lnb[c0], be1 = lnb[c1];
  float s0 = 0.f, s1 = 0.f;
  const int gw = blockIdx.x * 4 + wid, nwv = gridDim.x * 4;
  for (int n = gw; n < N; n += nwv) {
    // stage acc row; x_local[c] = (W_h . acc_h)/denom_h + b_conv
    myx[c0] = agg[(size_t)n * 128 + c0];
    myx[c1] = agg[(size_t)n * 128 + c1];
    float rd0 = 1.f / denom[(size_t)n * 8 + h0];
    float rd1 = 1.f / denom[(size_t)n * 8 + h1];
    float xl0 = 0.f, xl1 = 0.f;
#pragma unroll
    for (int d = 0; d < 16; ++d) {
      xl0 += myx[h0 * 16 + d] * W2t[d * 128 + c0];
      xl1 += myx[h1 * 16 + d] * W2t[d * 128 + c1];
    }
    float x0 = xl0 * rd0 + bc0;
    float x1 = xl1 * rd1 + bc1;
    myx[c0] = x0; myx[c1] = x1;
    // z1 = x_local @ fc_W^T + fc_b
    float z0 = fb0, z1 = fb1;
#pragma unroll
    for (int j = 0; j < 32; ++j) {
      float4 xv = myx4[j];
      float4 wa = fw[b0 | (j ^ ca)];
      float4 wb = fw[b1 | (j ^ ca)];
      z0 += xv.x * wa.x + xv.y * wa.y + xv.z * wa.z + xv.w * wa.w;
      z1 += xv.x * wb.x + xv.y * wb.y + xv.z * wb.z + xv.w * wb.w;
    }
    // att = softmax(leaky01(z)); xl2 = leaky02(x_local*att)
    float l0 = lrelu(z0, 0.01f), l1 = lrelu(z1, 0.01f);
    float m = wave_max64(fmaxf(l0, l1));
    float e0 = __expf(l0 - m), e1 = __expf(l1 - m);
    float sinv = 1.f / wave_sum64(e0 + e1);
    float y0 = lrelu(x0 * (e0 * sinv), 0.2f);
    float y1 = lrelu(x1 * (e1 * sinv), 0.2f);
    myx[c0] = y0; myx[c1] = y1;
    // z2 = xl2 @ fc_W^T + fc_b
    float w0 = fb0, w1 = fb1;
#pragma unroll
    for (int j = 0; j < 32; ++j) {
      float4 xv = myx4[j];
      float4 wa = fw[b0 | (j ^ ca)];
      float4 wb = fw[b1 | (j ^ ca)];
      w0 += xv.x * wa.x + xv.y * wa.y + xv.z * wa.z + xv.w * wa.w;
      w1 += xv.x * wb.x + xv.y * wb.y + xv.z * wb.z + xv.w * wb.w;
    }
    // LayerNorm + L2 normalize
    float mu = wave_sum64(w0 + w1) * (1.f / 128.f);
    float d0 = w0 - mu, d1 = w1 - mu;
    float var = wave_sum64(d0 * d0 + d1 * d1) * (1.f / 128.f);
    float rstd = rsqrtf(var + 1e-5f);
    float xn0 = d0 * rstd * g0 + be0;
    float xn1 = d1 * rstd * g1 + be1;
    float nrm = sqrtf(wave_sum64(xn0 * xn0 + xn1 * xn1));
    float rinv = 1.f / fmaxf(nrm, 1e-12f);
    xn0 *= rinv; xn1 *= rinv;
    out[(size_t)n * 128 + c0] = xn0;
    out[(size_t)n * 128 + c1] = xn1;
    s0 += xn0; s1 += xn1;
  }
  atomicAdd(colsum + c0, s0);
  atomicAdd(colsum + c1, s1);
}

// --- global attention vector ga[128] ---
__global__ void k_gatt(const float* __restrict__ colsum, const float* __restrict__ gW,
                       const float* __restrict__ gb, float* __restrict__ ga, int N) {
  __shared__ float xg[128], r[128];
  int t = threadIdx.x;
  xg[t] = colsum[t] / (float)N;
  __syncthreads();
  float acc = gb[t];
  for (int k = 0; k < 128; ++k) acc += xg[k] * gW[t * 128 + k];
  acc = fmaxf(acc, 0.f);
  r[t] = acc;
  __syncthreads();
  float m = -1e30f;
  for (int k = 0; k < 128; ++k) m = fmaxf(m, r[k]);
  float s = 0.f;
  for (int k = 0; k < 128; ++k) s += __expf(r[k] - m);
  ga[t] = __expf(acc - m) / s;
}

// --- out *= ga (broadcast over rows) ---
__global__ void k_scale(float* __restrict__ out, const float* __restrict__ ga, int total4) {
  float4* o4 = (float4*)out;
  const float4* g4 = (const float4*)ga;
  for (int i = blockIdx.x * blockDim.x + threadIdx.x; i < total4; i += gridDim.x * blockDim.x) {
    float4 v = o4[i];
    float4 g = g4[i & 31];
    v.x *= g.x; v.y *= g.y; v.z *= g.z; v.w *= g.w;
    o4[i] = v;
  }
}

extern "C" void kernel_launch(void* const* d_in, const int* in_sizes, int n_in,
                              void* d_out, int out_size, void* d_ws, size_t ws_size,
                              hipStream_t stream) {
  const float* x    = (const float*)d_in[0];
  const void*  ei   = d_in[1];
  const float* Wc   = (const float*)d_in[2];
  const float* asrc = (const float*)d_in[3];
  const float* adst = (const float*)d_in[4];
  const float* bcv  = (const float*)d_in[5];
  const float* fcW  = (const float*)d_in[6];
  const float* fcb  = (const float*)d_in[7];
  const float* lng  = (const float*)d_in[8];
  const float* lnb  = (const float*)d_in[9];
  const float* gW   = (const float*)d_in[10];
  const float* gb   = (const float*)d_in[11];
  const int N = in_sizes[0] / 16;
  const int E = in_sizes[1] / 2;

  float* als    = (float*)d_ws;                 // [N,8]
  float* ald    = als + (size_t)N * 8;          // [N,8]
  float* denom  = ald + (size_t)N * 8;          // [N,8]
  float* agg    = denom + (size_t)N * 8;        // [N,128] (h-major 16-dim accumulators)
  float* colsum = agg + (size_t)N * 128;        // [128]
  float* ga     = colsum + 128;                 // [128]
  int*   flag   = (int*)(ga + 128);             // [1]
  float* out    = (float*)d_out;

  hipMemsetAsync(denom, 0, ((size_t)N * 8 + (size_t)N * 128 + 128) * sizeof(float), stream);
  k_detect<<<1, 256, 0, stream>>>(ei, N, flag);
  k_alpha<<<(N + 255) / 256, 256, 0, stream>>>(x, Wc, asrc, adst, als, ald, N);
  k_edge<<<8192, 256, 0, stream>>>(ei, flag, x, als, ald, agg, denom, E, N);
  k_nodefc<<<2048, 256, 0, stream>>>(agg, denom, Wc, bcv, fcW, fcb, lng, lnb, out, colsum, N);
  k_gatt<<<1, 128, 0, stream>>>(colsum, gW, gb, ga, N);
  k_scale<<<4096, 256, 0, stream>>>(out, ga, N * 32);
}

// Round 2
// 1671.430 us; speedup vs baseline: 1.2709x; 1.2709x over previous
//
#include <hip/hip_runtime.h>

__device__ __forceinline__ float lrelu(float v, float s) { return v >= 0.f ? v : s * v; }

__device__ __forceinline__ float wave_sum64(float v) {
#pragma unroll
  for (int m = 1; m < 64; m <<= 1) v += __shfl_xor(v, m, 64);
  return v;
}
__device__ __forceinline__ float wave_max64(float v) {
#pragma unroll
  for (int m = 1; m < 64; m <<= 1) v = fmaxf(v, __shfl_xor(v, m, 64));
  return v;
}

// --- detect whether edge_index arrived as int64 or int32 ---
__global__ void k_detect(const void* __restrict__ ei, int N, int* __restrict__ flag) {
  __shared__ int bad;
  if (threadIdx.x == 0) bad = 0;
  __syncthreads();
  const long long* p = (const long long*)ei;
  int my = 0;
  for (int i = threadIdx.x; i < 1024; i += blockDim.x) {
    long long v = p[i];
    if (v < 0 || v >= (long long)N) my = 1;
  }
  if (my) atomicExch(&bad, 1);
  __syncthreads();
  if (threadIdx.x == 0) *flag = bad ? 0 : 1;  // 1 => int64
}

// --- per-node attention logits al_src/al_dst [N,8]; al = x . (W_h a_h) ---
__global__ void k_alpha(const float* __restrict__ x, const float* __restrict__ Wc,
                        const float* __restrict__ a_src, const float* __restrict__ a_dst,
                        float* __restrict__ als, float* __restrict__ ald, int N) {
  __shared__ float vs[128], vd[128];
  for (int t = threadIdx.x; t < 256; t += blockDim.x) {
    int h = (t & 127) >> 4, d = t & 15;
    const float* wrow = Wc + h * 256 + d * 16;
    const float* av = (t < 128 ? a_src : a_dst) + h * 16;
    float s = 0.f;
#pragma unroll
    for (int f = 0; f < 16; ++f) s += wrow[f] * av[f];
    if (t < 128) vs[h * 16 + d] = s; else vd[h * 16 + d] = s;
  }
  __syncthreads();
  for (int n = blockIdx.x * blockDim.x + threadIdx.x; n < N; n += gridDim.x * blockDim.x) {
    float xv[16];
    const float4* xr = (const float4*)(x + (size_t)n * 16);
#pragma unroll
    for (int q = 0; q < 4; ++q) {
      float4 t4 = xr[q];
      xv[q * 4 + 0] = t4.x; xv[q * 4 + 1] = t4.y; xv[q * 4 + 2] = t4.z; xv[q * 4 + 3] = t4.w;
    }
    float rs[8], rd[8];
#pragma unroll
    for (int h = 0; h < 8; ++h) {
      float s1 = 0.f, s2 = 0.f;
#pragma unroll
      for (int d = 0; d < 16; ++d) { s1 += xv[d] * vs[h * 16 + d]; s2 += xv[d] * vd[h * 16 + d]; }
      rs[h] = s1; rd[h] = s2;
    }
    float4* po = (float4*)(als + (size_t)n * 8);
    po[0] = make_float4(rs[0], rs[1], rs[2], rs[3]);
    po[1] = make_float4(rs[4], rs[5], rs[6], rs[7]);
    float4* pd = (float4*)(ald + (size_t)n * 8);
    pd[0] = make_float4(rd[0], rd[1], rd[2], rd[3]);
    pd[1] = make_float4(rd[4], rd[5], rd[6], rd[7]);
  }
}

// --- cnt[n] = 1 (self loop) ---
__global__ void k_init(int* __restrict__ cnt, int N) {
  for (int i = blockIdx.x * blockDim.x + threadIdx.x; i < N; i += gridDim.x * blockDim.x)
    cnt[i] = 1;
}

// --- histogram in-degree ---
__global__ void k_count(const void* __restrict__ ei, const int* __restrict__ flag,
                        int* __restrict__ cnt, int E) {
  const int is64 = *flag;
  for (int i = blockIdx.x * blockDim.x + threadIdx.x; i < E; i += gridDim.x * blockDim.x) {
    int d = is64 ? (int)((const long long*)ei)[(size_t)E + i] : ((const int*)ei)[(size_t)E + i];
    atomicAdd(&cnt[d], 1);
  }
}

// --- single-block exclusive scan of cnt[N] -> off[N+1], cursor[N] ---
__global__ __launch_bounds__(1024) void k_scan(const int* __restrict__ cnt,
                                               int* __restrict__ off, int* __restrict__ cursor,
                                               int N, int total) {
  __shared__ int part[1024];
  const int t = threadIdx.x;
  const int chunk = (N + 1023) >> 10;
  const int b = t * chunk, e = min(b + chunk, N);
  int s = 0;
  for (int i = b; i < e; ++i) s += cnt[i];
  part[t] = s;
  __syncthreads();
  for (int d = 1; d < 1024; d <<= 1) {
    int u = (t >= d) ? part[t - d] : 0;
    __syncthreads();
    part[t] += u;
    __syncthreads();
  }
  int run = part[t] - s;  // exclusive prefix of this thread's chunk
  for (int i = b; i < e; ++i) {
    int c = cnt[i];
    off[i] = run; cursor[i] = run;
    run += c;
  }
  if (t == 1023) off[N] = total;
}

// --- scatter edge sources into CSR slots (incl self loops) ---
__global__ void k_fill(const void* __restrict__ ei, const int* __restrict__ flag,
                       int* __restrict__ cursor, int* __restrict__ srcs, int E, int N) {
  const int is64 = *flag;
  const int EE = E + N;
  for (int i = blockIdx.x * blockDim.x + threadIdx.x; i < EE; i += gridDim.x * blockDim.x) {
    int s, d;
    if (i < E) {
      if (is64) { s = (int)((const long long*)ei)[i]; d = (int)((const long long*)ei)[(size_t)E + i]; }
      else      { s = ((const int*)ei)[i];            d = ((const int*)ei)[(size_t)E + i]; }
    } else { s = d = i - E; }
    int slot = atomicAdd(&cursor[d], 1);
    srcs[slot] = s;
  }
}

// --- fused gather-aggregate + dense chain. One wave per node. ---
__global__ __launch_bounds__(256) void k_fused(
    const float* __restrict__ x, const int* __restrict__ off, const int* __restrict__ srcs,
    const float* __restrict__ als, const float* __restrict__ ald,
    const float* __restrict__ Wc, const float* __restrict__ b_conv,
    const float* __restrict__ fcW, const float* __restrict__ fcb,
    const float* __restrict__ lng, const float* __restrict__ lnb,
    float* __restrict__ out, float* __restrict__ colsum, int N) {
  __shared__ float4 fw[4096];      // fc_W rows, XOR-swizzled float4 chunks (64KB)
  __shared__ float W2t[2048];      // W_conv as [d][h*16+f] (8KB)
  __shared__ __align__(16) float4 xls4[4][32];  // per-wave 128-float buffer
  __shared__ float dsh[4][8];      // per-wave per-head denom
  const float4* fwg = (const float4*)fcW;
  for (int i = threadIdx.x; i < 4096; i += blockDim.x) {
    int c = i >> 5, j = i & 31;
    fw[(c << 5) | (j ^ (c & 31))] = fwg[i];
  }
  for (int i = threadIdx.x; i < 2048; i += blockDim.x) {
    int h = i >> 8, d = (i >> 4) & 15, f = i & 15;
    W2t[d * 128 + h * 16 + f] = Wc[i];
  }
  __syncthreads();
  const int wid = threadIdx.x >> 6, lane = threadIdx.x & 63;
  const int h = lane >> 3, dp = lane & 7;       // gather-phase mapping
  const int c0 = lane, c1 = lane + 64;          // dense-phase mapping
  const int h0 = lane >> 4, h1 = h0 + 4;
  const int ca = lane & 31;
  float* myx = (float*)xls4[wid];
  const float4* myx4 = xls4[wid];
  const int b0 = c0 << 5, b1 = c1 << 5;
  const float fb0 = fcb[c0], fb1 = fcb[c1];
  const float bc0 = b_conv[c0], bc1 = b_conv[c1];
  const float g0 = lng[c0], g1 = lng[c1];
  const float be0 = lnb[c0], be1 = lnb[c1];
  float s0 = 0.f, s1 = 0.f;
  const int gw = blockIdx.x * 4 + wid, nwv = gridDim.x * 4;
  for (int n = gw; n < N; n += nwv) {
    const int beg = off[n], end = off[n + 1];
    const float aldh = ald[(size_t)n * 8 + h];
    float acc0 = 0.f, acc1 = 0.f, den = 0.f;
    int i = beg;
    int snext = srcs[beg];                       // deg >= 1 (self loop)
    while (i < end) {
      const int s = snext;
      ++i;
      if (i < end) snext = srcs[i];
      const float w = __expf(lrelu(als[(size_t)s * 8 + h] + aldh, 0.2f));
      const float2 xv = ((const float2*)(x + (size_t)s * 16))[dp];
      acc0 += w * xv.x; acc1 += w * xv.y; den += w;
    }
    myx[h * 16 + dp * 2] = acc0;
    myx[h * 16 + dp * 2 + 1] = acc1;
    if (dp == 0) dsh[wid][h] = den;
    // x_local[c] = (W_h . acc_h)/denom_h + b_conv
    const float rd0 = 1.f / dsh[wid][h0];
    const float rd1 = 1.f / dsh[wid][h1];
    float xl0 = 0.f, xl1 = 0.f;
#pragma unroll
    for (int d = 0; d < 16; ++d) {
      xl0 += myx[h0 * 16 + d] * W2t[d * 128 + c0];
      xl1 += myx[h1 * 16 + d] * W2t[d * 128 + c1];
    }
    const float x0 = xl0 * rd0 + bc0;
    const float x1 = xl1 * rd1 + bc1;
    myx[c0] = x0; myx[c1] = x1;
    // z1 = x_local @ fc_W^T + fc_b
    float z0 = fb0, z1 = fb1;
#pragma unroll
    for (int j = 0; j < 32; ++j) {
      float4 xv = myx4[j];
      float4 wa = fw[b0 | (j ^ ca)];
      float4 wb = fw[b1 | (j ^ ca)];
      z0 += xv.x * wa.x + xv.y * wa.y + xv.z * wa.z + xv.w * wa.w;
      z1 += xv.x * wb.x + xv.y * wb.y + xv.z * wb.z + xv.w * wb.w;
    }
    // att = softmax(leaky01(z)); xl2 = leaky02(x_local*att)
    const float l0 = lrelu(z0, 0.01f), l1 = lrelu(z1, 0.01f);
    const float m = wave_max64(fmaxf(l0, l1));
    const float e0 = __expf(l0 - m), e1 = __expf(l1 - m);
    const float sinv = 1.f / wave_sum64(e0 + e1);
    const float y0 = lrelu(x0 * (e0 * sinv), 0.2f);
    const float y1 = lrelu(x1 * (e1 * sinv), 0.2f);
    myx[c0] = y0; myx[c1] = y1;
    // z2 = xl2 @ fc_W^T + fc_b
    float w0 = fb0, w1 = fb1;
#pragma unroll
    for (int j = 0; j < 32; ++j) {
      float4 xv = myx4[j];
      float4 wa = fw[b0 | (j ^ ca)];
      float4 wb = fw[b1 | (j ^ ca)];
      w0 += xv.x * wa.x + xv.y * wa.y + xv.z * wa.z + xv.w * wa.w;
      w1 += xv.x * wb.x + xv.y * wb.y + xv.z * wb.z + xv.w * wb.w;
    }
    // LayerNorm + L2 normalize
    const float mu = wave_sum64(w0 + w1) * (1.f / 128.f);
    const float d0 = w0 - mu, d1 = w1 - mu;
    const float var = wave_sum64(d0 * d0 + d1 * d1) * (1.f / 128.f);
    const float rstd = rsqrtf(var + 1e-5f);
    float xn0 = d0 * rstd * g0 + be0;
    float xn1 = d1 * rstd * g1 + be1;
    const float nrm = sqrtf(wave_sum64(xn0 * xn0 + xn1 * xn1));
    const float rinv = 1.f / fmaxf(nrm, 1e-12f);
    xn0 *= rinv; xn1 *= rinv;
    out[(size_t)n * 128 + c0] = xn0;
    out[(size_t)n * 128 + c1] = xn1;
    s0 += xn0; s1 += xn1;
  }
  atomicAdd(colsum + c0, s0);
  atomicAdd(colsum + c1, s1);
}

// --- global attention vector ga[128] ---
__global__ void k_gatt(const float* __restrict__ colsum, const float* __restrict__ gW,
                       const float* __restrict__ gb, float* __restrict__ ga, int N) {
  __shared__ float xg[128], r[128];
  int t = threadIdx.x;
  xg[t] = colsum[t] / (float)N;
  __syncthreads();
  float acc = gb[t];
  for (int k = 0; k < 128; ++k) acc += xg[k] * gW[t * 128 + k];
  acc = fmaxf(acc, 0.f);
  r[t] = acc;
  __syncthreads();
  float m = -1e30f;
  for (int k = 0; k < 128; ++k) m = fmaxf(m, r[k]);
  float s = 0.f;
  for (int k = 0; k < 128; ++k) s += __expf(r[k] - m);
  ga[t] = __expf(acc - m) / s;
}

// --- out *= ga (broadcast over rows) ---
__global__ void k_scale(float* __restrict__ out, const float* __restrict__ ga, int total4) {
  float4* o4 = (float4*)out;
  const float4* g4 = (const float4*)ga;
  for (int i = blockIdx.x * blockDim.x + threadIdx.x; i < total4; i += gridDim.x * blockDim.x) {
    float4 v = o4[i];
    float4 g = g4[i & 31];
    v.x *= g.x; v.y *= g.y; v.z *= g.z; v.w *= g.w;
    o4[i] = v;
  }
}

extern "C" void kernel_launch(void* const* d_in, const int* in_sizes, int n_in,
                              void* d_out, int out_size, void* d_ws, size_t ws_size,
                              hipStream_t stream) {
  const float* x    = (const float*)d_in[0];
  const void*  ei   = d_in[1];
  const float* Wc   = (const float*)d_in[2];
  const float* asrc = (const float*)d_in[3];
  const float* adst = (const float*)d_in[4];
  const float* bcv  = (const float*)d_in[5];
  const float* fcW  = (const float*)d_in[6];
  const float* fcb  = (const float*)d_in[7];
  const float* lng  = (const float*)d_in[8];
  const float* lnb  = (const float*)d_in[9];
  const float* gW   = (const float*)d_in[10];
  const float* gb   = (const float*)d_in[11];
  const int N = in_sizes[0] / 16;
  const int E = in_sizes[1] / 2;
  const int EE = E + N;

  float* als    = (float*)d_ws;                 // [N,8]
  float* ald    = als + (size_t)N * 8;          // [N,8]
  float* colsum = ald + (size_t)N * 8;          // [128]
  float* ga     = colsum + 128;                 // [128]
  int*   flag   = (int*)(ga + 128);             // [1]
  int*   cnt    = flag + 1;                     // [N]
  int*   off    = cnt + N;                      // [N+1]
  int*   cursor = off + N + 1;                  // [N]
  int*   srcs   = cursor + N;                   // [E+N]
  float* out    = (float*)d_out;

  hipMemsetAsync(colsum, 0, 128 * sizeof(float), stream);
  k_detect<<<1, 256, 0, stream>>>(ei, N, flag);
  k_init<<<128, 256, 0, stream>>>(cnt, N);
  k_alpha<<<512, 256, 0, stream>>>(x, Wc, asrc, adst, als, ald, N);
  k_count<<<2048, 256, 0, stream>>>(ei, flag, cnt, E);
  k_scan<<<1, 1024, 0, stream>>>(cnt, off, cursor, N, EE);
  k_fill<<<2048, 256, 0, stream>>>(ei, flag, cursor, srcs, E, N);
  k_fused<<<2048, 256, 0, stream>>>(x, off, srcs, als, ald, Wc, bcv, fcW, fcb,
                                    lng, lnb, out, colsum, N);
  k_gatt<<<1, 128, 0, stream>>>(colsum, gW, gb, ga, N);
  k_scale<<<4096, 256, 0, stream>>>(out, ga, N * 32);
}

// Round 3
// 701.956 us; speedup vs baseline: 3.0261x; 2.3811x over previous
//
#include <hip/hip_runtime.h>

__device__ __forceinline__ float lrelu(float v, float s) { return v >= 0.f ? v : s * v; }

__device__ __forceinline__ float wave_sum64(float v) {
#pragma unroll
  for (int m = 1; m < 64; m <<= 1) v += __shfl_xor(v, m, 64);
  return v;
}
__device__ __forceinline__ float wave_max64(float v) {
#pragma unroll
  for (int m = 1; m < 64; m <<= 1) v = fmaxf(v, __shfl_xor(v, m, 64));
  return v;
}
__device__ __forceinline__ float rdlane(float v, int l) {
  return __uint_as_float(__builtin_amdgcn_readlane(__float_as_uint(v), l));
}

// --- detect whether edge_index arrived as int64 or int32 ---
__global__ void k_detect(const void* __restrict__ ei, int N, int* __restrict__ flag) {
  __shared__ int bad;
  if (threadIdx.x == 0) bad = 0;
  __syncthreads();
  const long long* p = (const long long*)ei;
  int my = 0;
  for (int i = threadIdx.x; i < 1024; i += blockDim.x) {
    long long v = p[i];
    if (v < 0 || v >= (long long)N) my = 1;
  }
  if (my) atomicExch(&bad, 1);
  __syncthreads();
  if (threadIdx.x == 0) *flag = bad ? 0 : 1;  // 1 => int64
}

// --- per-node attention logits al_src/al_dst [N,8]; al = x . (W_h a_h) ---
__global__ void k_alpha(const float* __restrict__ x, const float* __restrict__ Wc,
                        const float* __restrict__ a_src, const float* __restrict__ a_dst,
                        float* __restrict__ als, float* __restrict__ ald, int N) {
  __shared__ float vs[128], vd[128];
  for (int t = threadIdx.x; t < 256; t += blockDim.x) {
    int h = (t & 127) >> 4, d = t & 15;
    const float* wrow = Wc + h * 256 + d * 16;
    const float* av = (t < 128 ? a_src : a_dst) + h * 16;
    float s = 0.f;
#pragma unroll
    for (int f = 0; f < 16; ++f) s += wrow[f] * av[f];
    if (t < 128) vs[h * 16 + d] = s; else vd[h * 16 + d] = s;
  }
  __syncthreads();
  for (int n = blockIdx.x * blockDim.x + threadIdx.x; n < N; n += gridDim.x * blockDim.x) {
    float xv[16];
    const float4* xr = (const float4*)(x + (size_t)n * 16);
#pragma unroll
    for (int q = 0; q < 4; ++q) {
      float4 t4 = xr[q];
      xv[q * 4 + 0] = t4.x; xv[q * 4 + 1] = t4.y; xv[q * 4 + 2] = t4.z; xv[q * 4 + 3] = t4.w;
    }
    float rs[8], rd[8];
#pragma unroll
    for (int h = 0; h < 8; ++h) {
      float s1 = 0.f, s2 = 0.f;
#pragma unroll
      for (int d = 0; d < 16; ++d) { s1 += xv[d] * vs[h * 16 + d]; s2 += xv[d] * vd[h * 16 + d]; }
      rs[h] = s1; rd[h] = s2;
    }
    float4* po = (float4*)(als + (size_t)n * 8);
    po[0] = make_float4(rs[0], rs[1], rs[2], rs[3]);
    po[1] = make_float4(rs[4], rs[5], rs[6], rs[7]);
    float4* pd = (float4*)(ald + (size_t)n * 8);
    pd[0] = make_float4(rd[0], rd[1], rd[2], rd[3]);
    pd[1] = make_float4(rd[4], rd[5], rd[6], rd[7]);
  }
}

// --- cnt[n] = 1 (self loop) ---
__global__ void k_init(int* __restrict__ cnt, int N) {
  for (int i = blockIdx.x * blockDim.x + threadIdx.x; i < N; i += gridDim.x * blockDim.x)
    cnt[i] = 1;
}

// --- histogram in-degree ---
__global__ void k_count(const void* __restrict__ ei, const int* __restrict__ flag,
                        int* __restrict__ cnt, int E) {
  const int is64 = *flag;
  for (int i = blockIdx.x * blockDim.x + threadIdx.x; i < E; i += gridDim.x * blockDim.x) {
    int d = is64 ? (int)((const long long*)ei)[(size_t)E + i] : ((const int*)ei)[(size_t)E + i];
    atomicAdd(&cnt[d], 1);
  }
}

// --- single-block exclusive scan (wave-strip, coalesced) ---
__global__ __launch_bounds__(1024) void k_scan(const int* __restrict__ cnt,
                                               int* __restrict__ off, int* __restrict__ cursor,
                                               int N, int total) {
  __shared__ int wtot[16];
  const int t = threadIdx.x, wid = t >> 6, lane = t & 63;
  const int per = ((N + 1023) >> 10) << 6;  // elems per wave, multiple of 64
  const int base = wid * per;
  const int lim = min(base + per, N);
  // pass 1: per-wave totals
  int part = 0;
  for (int i = base + lane; i < lim; i += 64) part += cnt[i];
#pragma unroll
  for (int m = 1; m < 64; m <<= 1) part += __shfl_xor(part, m, 64);
  if (lane == 0) wtot[wid] = part;
  __syncthreads();
  int wbase = 0;
  for (int w = 0; w < wid; ++w) wbase += wtot[w];
  // pass 2: write offsets
  int running = wbase;
  for (int i0 = base; i0 < lim; i0 += 64) {
    int i = i0 + lane;
    int c = (i < N) ? cnt[i] : 0;
    int v = c;
#pragma unroll
    for (int d = 1; d < 64; d <<= 1) {
      int u = __shfl_up(v, d, 64);
      if (lane >= d) v += u;
    }
    if (i < N) { int o = running + v - c; off[i] = o; cursor[i] = o; }
    running += __shfl(v, 63, 64);
  }
  if (t == 0) off[N] = total;
}

// --- scatter edge sources into CSR slots (incl self loops) ---
__global__ void k_fill(const void* __restrict__ ei, const int* __restrict__ flag,
                       int* __restrict__ cursor, int* __restrict__ srcs, int E, int N) {
  const int is64 = *flag;
  const int EE = E + N;
  for (int i = blockIdx.x * blockDim.x + threadIdx.x; i < EE; i += gridDim.x * blockDim.x) {
    int s, d;
    if (i < E) {
      if (is64) { s = (int)((const long long*)ei)[i]; d = (int)((const long long*)ei)[(size_t)E + i]; }
      else      { s = ((const int*)ei)[i];            d = ((const int*)ei)[(size_t)E + i]; }
    } else { s = d = i - E; }
    int slot = atomicAdd(&cursor[d], 1);
    srcs[slot] = s;
  }
}

// --- gather-aggregate + W_conv apply -> xlocal[N,128]. One wave per node,
//     8 edges per iteration: lane = edge-slot(es=lane>>3) x head(h=lane&7). ---
__global__ __launch_bounds__(256) void k_xlocal(
    const float* __restrict__ x, const int* __restrict__ off, const int* __restrict__ srcs,
    const float* __restrict__ als, const float* __restrict__ ald,
    const float* __restrict__ Wc, const float* __restrict__ b_conv,
    float* __restrict__ xlocal, int N) {
  __shared__ float W2t[2048];     // [d][h*16+f]
  __shared__ float myx[4][128];
  __shared__ float dsh[4][8];
  for (int i = threadIdx.x; i < 2048; i += blockDim.x) {
    int h = i >> 8, d = (i >> 4) & 15, f = i & 15;
    W2t[d * 128 + h * 16 + f] = Wc[i];
  }
  __syncthreads();
  const int wid = threadIdx.x >> 6, lane = threadIdx.x & 63;
  const int es = lane >> 3, h = lane & 7;
  const int c0 = lane, c1 = lane + 64;
  const int h0 = lane >> 4, h1 = h0 + 4;
  const float bc0 = b_conv[c0], bc1 = b_conv[c1];
  const int gw = blockIdx.x * 4 + wid, nwv = gridDim.x * 4;
  for (int n = gw; n < N; n += nwv) {
    const int beg = off[n], end = off[n + 1];
    const float aldh = ald[(size_t)n * 8 + h];
    float acc[16];
#pragma unroll
    for (int d = 0; d < 16; ++d) acc[d] = 0.f;
    float den = 0.f;
    // prologue: load strip 0
    int s = srcs[min(beg + es, end - 1)];
    float av = als[(size_t)s * 8 + h];
    const float4* xr = (const float4*)(x + (size_t)s * 16);
    float4 v0 = xr[0], v1 = xr[1], v2 = xr[2], v3 = xr[3];
    for (int base = beg; base < end; base += 8) {
      // prefetch next strip (clamped; always-safe addresses)
      int sn = srcs[min(base + 8 + es, end - 1)];
      float avn = als[(size_t)sn * 8 + h];
      const float4* xrn = (const float4*)(x + (size_t)sn * 16);
      float4 n0 = xrn[0], n1 = xrn[1], n2 = xrn[2], n3 = xrn[3];
      // compute current strip
      float e = av + aldh;
      float w = ((base + es) < end) ? __expf(e >= 0.f ? e : 0.2f * e) : 0.f;
      den += w;
      acc[0] += w * v0.x;  acc[1] += w * v0.y;  acc[2] += w * v0.z;  acc[3] += w * v0.w;
      acc[4] += w * v1.x;  acc[5] += w * v1.y;  acc[6] += w * v1.z;  acc[7] += w * v1.w;
      acc[8] += w * v2.x;  acc[9] += w * v2.y;  acc[10] += w * v2.z; acc[11] += w * v2.w;
      acc[12] += w * v3.x; acc[13] += w * v3.y; acc[14] += w * v3.z; acc[15] += w * v3.w;
      s = sn; av = avn; v0 = n0; v1 = n1; v2 = n2; v3 = n3;
    }
    // reduce across the 8 edge-slots (lanes h, h+8, ..., h+56)
#pragma unroll
    for (int m = 8; m < 64; m <<= 1) {
#pragma unroll
      for (int d = 0; d < 16; ++d) acc[d] += __shfl_xor(acc[d], m, 64);
      den += __shfl_xor(den, m, 64);
    }
    if (es == 0) {
#pragma unroll
      for (int d = 0; d < 16; ++d) myx[wid][h * 16 + d] = acc[d];
      dsh[wid][h] = den;
    }
    // x_local[c] = (W_h . acc_h)/den_h + b_conv[c]
    const float rd0 = 1.f / dsh[wid][h0];
    const float rd1 = 1.f / dsh[wid][h1];
    float xl0 = 0.f, xl1 = 0.f;
#pragma unroll
    for (int d = 0; d < 16; ++d) {
      xl0 += myx[wid][h0 * 16 + d] * W2t[d * 128 + c0];
      xl1 += myx[wid][h1 * 16 + d] * W2t[d * 128 + c1];
    }
    xlocal[(size_t)n * 128 + c0] = xl0 * rd0 + bc0;
    xlocal[(size_t)n * 128 + c1] = xl1 * rd1 + bc1;
  }
}

// --- dense chain, 4 nodes per wave; fc_W in LDS (swizzled), x broadcast via readlane ---
#define MATVEC_HALF(XS, JBASE)                                                 \
  _Pragma("unroll 4") for (int j2 = 0; j2 < 16; ++j2) {                        \
    const int j = (JBASE) + j2;                                                \
    const float4 wa = fw[b0 | (j ^ ca)];                                       \
    const float4 wb = fw[b1 | (j ^ ca)];                                       \
    const int srcl = 4 * j2;                                                   \
    _Pragma("unroll") for (int nn = 0; nn < 4; ++nn) {                         \
      const float a0 = rdlane(XS[nn], srcl);                                   \
      const float a1 = rdlane(XS[nn], srcl + 1);                               \
      const float a2 = rdlane(XS[nn], srcl + 2);                               \
      const float a3 = rdlane(XS[nn], srcl + 3);                               \
      z0[nn] += a0 * wa.x + a1 * wa.y + a2 * wa.z + a3 * wa.w;                 \
      z1[nn] += a0 * wb.x + a1 * wb.y + a2 * wb.z + a3 * wb.w;                 \
    }                                                                          \
  }

__global__ __launch_bounds__(256) void k_dense(
    float* __restrict__ xlocal,   // in-place: rows read then overwritten
    const float* __restrict__ fcW, const float* __restrict__ fcb,
    const float* __restrict__ lng, const float* __restrict__ lnb,
    float* __restrict__ colsum, int N) {
  __shared__ float4 fw[4096];   // fc_W rows, XOR-swizzled float4 chunks (64KB)
  const float4* fwg = (const float4*)fcW;
  for (int i = threadIdx.x; i < 4096; i += blockDim.x) {
    int c = i >> 5, j = i & 31;
    fw[(c << 5) | (j ^ (c & 31))] = fwg[i];
  }
  __syncthreads();
  const int wid = threadIdx.x >> 6, lane = threadIdx.x & 63;
  const int c0 = lane, c1 = lane + 64;
  const int ca = lane & 31;
  const int b0 = c0 << 5, b1 = c1 << 5;
  const float fb0 = fcb[c0], fb1 = fcb[c1];
  const float g0 = lng[c0], g1 = lng[c1];
  const float be0 = lnb[c0], be1 = lnb[c1];
  float s0 = 0.f, s1 = 0.f;
  const int ngroups = (N + 3) >> 2;
  const int gw = blockIdx.x * 4 + wid, nwv = gridDim.x * 4;
  for (int g = gw; g < ngroups; g += nwv) {
    const int nb = g * 4;
    float xs0[4], xs1[4];
#pragma unroll
    for (int nn = 0; nn < 4; ++nn) {
      const size_t r = (size_t)min(nb + nn, N - 1) * 128;
      xs0[nn] = xlocal[r + c0];
      xs1[nn] = xlocal[r + c1];
    }
    float z0[4], z1[4];
#pragma unroll
    for (int nn = 0; nn < 4; ++nn) { z0[nn] = fb0; z1[nn] = fb1; }
    MATVEC_HALF(xs0, 0)
    MATVEC_HALF(xs1, 16)
    float y0[4], y1[4];
#pragma unroll
    for (int nn = 0; nn < 4; ++nn) {
      const float l0 = lrelu(z0[nn], 0.01f), l1 = lrelu(z1[nn], 0.01f);
      const float m = wave_max64(fmaxf(l0, l1));
      const float e0 = __expf(l0 - m), e1 = __expf(l1 - m);
      const float sinv = 1.f / wave_sum64(e0 + e1);
      y0[nn] = lrelu(xs0[nn] * (e0 * sinv), 0.2f);
      y1[nn] = lrelu(xs1[nn] * (e1 * sinv), 0.2f);
    }
#pragma unroll
    for (int nn = 0; nn < 4; ++nn) { z0[nn] = fb0; z1[nn] = fb1; }
    MATVEC_HALF(y0, 0)
    MATVEC_HALF(y1, 16)
#pragma unroll
    for (int nn = 0; nn < 4; ++nn) {
      const float mu = wave_sum64(z0[nn] + z1[nn]) * (1.f / 128.f);
      const float d0 = z0[nn] - mu, d1 = z1[nn] - mu;
      const float var = wave_sum64(d0 * d0 + d1 * d1) * (1.f / 128.f);
      const float rstd = rsqrtf(var + 1e-5f);
      float xn0 = d0 * rstd * g0 + be0;
      float xn1 = d1 * rstd * g1 + be1;
      const float nrm = sqrtf(wave_sum64(xn0 * xn0 + xn1 * xn1));
      const float rinv = 1.f / fmaxf(nrm, 1e-12f);
      xn0 *= rinv; xn1 *= rinv;
      const int n = nb + nn;
      if (n < N) {
        xlocal[(size_t)n * 128 + c0] = xn0;
        xlocal[(size_t)n * 128 + c1] = xn1;
        s0 += xn0; s1 += xn1;
      }
    }
  }
  atomicAdd(colsum + c0, s0);
  atomicAdd(colsum + c1, s1);
}

// --- global attention vector ga[128] ---
__global__ void k_gatt(const float* __restrict__ colsum, const float* __restrict__ gW,
                       const float* __restrict__ gb, float* __restrict__ ga, int N) {
  __shared__ float xg[128], r[128];
  int t = threadIdx.x;
  xg[t] = colsum[t] / (float)N;
  __syncthreads();
  float acc = gb[t];
  for (int k = 0; k < 128; ++k) acc += xg[k] * gW[t * 128 + k];
  acc = fmaxf(acc, 0.f);
  r[t] = acc;
  __syncthreads();
  float m = -1e30f;
  for (int k = 0; k < 128; ++k) m = fmaxf(m, r[k]);
  float s = 0.f;
  for (int k = 0; k < 128; ++k) s += __expf(r[k] - m);
  ga[t] = __expf(acc - m) / s;
}

// --- out *= ga (broadcast over rows) ---
__global__ void k_scale(float* __restrict__ out, const float* __restrict__ ga, int total4) {
  float4* o4 = (float4*)out;
  const float4* g4 = (const float4*)ga;
  for (int i = blockIdx.x * blockDim.x + threadIdx.x; i < total4; i += gridDim.x * blockDim.x) {
    float4 v = o4[i];
    float4 g = g4[i & 31];
    v.x *= g.x; v.y *= g.y; v.z *= g.z; v.w *= g.w;
    o4[i] = v;
  }
}

extern "C" void kernel_launch(void* const* d_in, const int* in_sizes, int n_in,
                              void* d_out, int out_size, void* d_ws, size_t ws_size,
                              hipStream_t stream) {
  const float* x    = (const float*)d_in[0];
  const void*  ei   = d_in[1];
  const float* Wc   = (const float*)d_in[2];
  const float* asrc = (const float*)d_in[3];
  const float* adst = (const float*)d_in[4];
  const float* bcv  = (const float*)d_in[5];
  const float* fcW  = (const float*)d_in[6];
  const float* fcb  = (const float*)d_in[7];
  const float* lng  = (const float*)d_in[8];
  const float* lnb  = (const float*)d_in[9];
  const float* gW   = (const float*)d_in[10];
  const float* gb   = (const float*)d_in[11];
  const int N = in_sizes[0] / 16;
  const int E = in_sizes[1] / 2;
  const int EE = E + N;

  float* als    = (float*)d_ws;                 // [N,8]
  float* ald    = als + (size_t)N * 8;          // [N,8]
  float* colsum = ald + (size_t)N * 8;          // [128]
  float* ga     = colsum + 128;                 // [128]
  int*   flag   = (int*)(ga + 128);             // [1]
  int*   cnt    = flag + 1;                     // [N]
  int*   off    = cnt + N;                      // [N+1]
  int*   cursor = off + N + 1;                  // [N]
  int*   srcs   = cursor + N;                   // [E+N]
  float* out    = (float*)d_out;                // doubles as xlocal

  hipMemsetAsync(colsum, 0, 128 * sizeof(float), stream);
  k_detect<<<1, 256, 0, stream>>>(ei, N, flag);
  k_init<<<128, 256, 0, stream>>>(cnt, N);
  k_alpha<<<512, 256, 0, stream>>>(x, Wc, asrc, adst, als, ald, N);
  k_count<<<1024, 256, 0, stream>>>(ei, flag, cnt, E);
  k_scan<<<1, 1024, 0, stream>>>(cnt, off, cursor, N, EE);
  k_fill<<<1024, 256, 0, stream>>>(ei, flag, cursor, srcs, E, N);
  k_xlocal<<<2048, 256, 0, stream>>>(x, off, srcs, als, ald, Wc, bcv, out, N);
  k_dense<<<1024, 256, 0, stream>>>(out, fcW, fcb, lng, lnb, colsum, N);
  k_gatt<<<1, 128, 0, stream>>>(colsum, gW, gb, ga, N);
  k_scale<<<2048, 256, 0, stream>>>(out, ga, N * 32);
}

// Round 4
// 515.970 us; speedup vs baseline: 4.1169x; 1.3605x over previous
//
#include <hip/hip_runtime.h>

typedef __attribute__((ext_vector_type(8))) short bf16x8;
typedef __attribute__((ext_vector_type(4))) float f32x4;

__device__ __forceinline__ float lrelu(float v, float s) { return v >= 0.f ? v : s * v; }

__device__ __forceinline__ float wave_sum64(float v) {
#pragma unroll
  for (int m = 1; m < 64; m <<= 1) v += __shfl_xor(v, m, 64);
  return v;
}
__device__ __forceinline__ short bf16t(float f) {
  return (short)(__float_as_uint(f) >> 16);
}

// --- detect whether edge_index arrived as int64 or int32 ---
__global__ void k_detect(const void* __restrict__ ei, int N, int* __restrict__ flag) {
  __shared__ int bad;
  if (threadIdx.x == 0) bad = 0;
  __syncthreads();
  const long long* p = (const long long*)ei;
  int my = 0;
  for (int i = threadIdx.x; i < 1024; i += blockDim.x) {
    long long v = p[i];
    if (v < 0 || v >= (long long)N) my = 1;
  }
  if (my) atomicExch(&bad, 1);
  __syncthreads();
  if (threadIdx.x == 0) *flag = bad ? 0 : 1;  // 1 => int64
}

// --- per-node attention logits al_src/al_dst [N,8]; al = x . (W_h a_h) ---
__global__ void k_alpha(const float* __restrict__ x, const float* __restrict__ Wc,
                        const float* __restrict__ a_src, const float* __restrict__ a_dst,
                        float* __restrict__ als, float* __restrict__ ald, int N) {
  __shared__ float vs[128], vd[128];
  for (int t = threadIdx.x; t < 256; t += blockDim.x) {
    int h = (t & 127) >> 4, d = t & 15;
    const float* wrow = Wc + h * 256 + d * 16;
    const float* av = (t < 128 ? a_src : a_dst) + h * 16;
    float s = 0.f;
#pragma unroll
    for (int f = 0; f < 16; ++f) s += wrow[f] * av[f];
    if (t < 128) vs[h * 16 + d] = s; else vd[h * 16 + d] = s;
  }
  __syncthreads();
  for (int n = blockIdx.x * blockDim.x + threadIdx.x; n < N; n += gridDim.x * blockDim.x) {
    float xv[16];
    const float4* xr = (const float4*)(x + (size_t)n * 16);
#pragma unroll
    for (int q = 0; q < 4; ++q) {
      float4 t4 = xr[q];
      xv[q * 4 + 0] = t4.x; xv[q * 4 + 1] = t4.y; xv[q * 4 + 2] = t4.z; xv[q * 4 + 3] = t4.w;
    }
    float rs[8], rd[8];
#pragma unroll
    for (int h = 0; h < 8; ++h) {
      float s1 = 0.f, s2 = 0.f;
#pragma unroll
      for (int d = 0; d < 16; ++d) { s1 += xv[d] * vs[h * 16 + d]; s2 += xv[d] * vd[h * 16 + d]; }
      rs[h] = s1; rd[h] = s2;
    }
    float4* po = (float4*)(als + (size_t)n * 8);
    po[0] = make_float4(rs[0], rs[1], rs[2], rs[3]);
    po[1] = make_float4(rs[4], rs[5], rs[6], rs[7]);
    float4* pd = (float4*)(ald + (size_t)n * 8);
    pd[0] = make_float4(rd[0], rd[1], rd[2], rd[3]);
    pd[1] = make_float4(rd[4], rd[5], rd[6], rd[7]);
  }
}

// --- cnt[n] = 1 (self loop) ---
__global__ void k_init(int* __restrict__ cnt, int N) {
  for (int i = blockIdx.x * blockDim.x + threadIdx.x; i < N; i += gridDim.x * blockDim.x)
    cnt[i] = 1;
}

// --- histogram in-degree ---
__global__ void k_count(const void* __restrict__ ei, const int* __restrict__ flag,
                        int* __restrict__ cnt, int E) {
  const int is64 = *flag;
  for (int i = blockIdx.x * blockDim.x + threadIdx.x; i < E; i += gridDim.x * blockDim.x) {
    int d = is64 ? (int)((const long long*)ei)[(size_t)E + i] : ((const int*)ei)[(size_t)E + i];
    atomicAdd(&cnt[d], 1);
  }
}

// --- single-block exclusive scan (wave-strip, coalesced) ---
__global__ __launch_bounds__(1024) void k_scan(const int* __restrict__ cnt,
                                               int* __restrict__ off, int* __restrict__ cursor,
                                               int N, int total) {
  __shared__ int wtot[16];
  const int t = threadIdx.x, wid = t >> 6, lane = t & 63;
  const int per = ((N + 1023) >> 10) << 6;  // elems per wave, multiple of 64
  const int base = wid * per;
  const int lim = min(base + per, N);
  // pass 1: per-wave totals
  int part = 0;
  for (int i = base + lane; i < lim; i += 64) part += cnt[i];
#pragma unroll
  for (int m = 1; m < 64; m <<= 1) part += __shfl_xor(part, m, 64);
  if (lane == 0) wtot[wid] = part;
  __syncthreads();
  int wbase = 0;
  for (int w = 0; w < wid; ++w) wbase += wtot[w];
  // pass 2: write offsets
  int running = wbase;
  for (int i0 = base; i0 < lim; i0 += 64) {
    int i = i0 + lane;
    int c = (i < N) ? cnt[i] : 0;
    int v = c;
#pragma unroll
    for (int d = 1; d < 64; d <<= 1) {
      int u = __shfl_up(v, d, 64);
      if (lane >= d) v += u;
    }
    if (i < N) { int o = running + v - c; off[i] = o; cursor[i] = o; }
    running += __shfl(v, 63, 64);
  }
  if (t == 0) off[N] = total;
}

// --- scatter edge sources into CSR slots (incl self loops) ---
__global__ void k_fill(const void* __restrict__ ei, const int* __restrict__ flag,
                       int* __restrict__ cursor, int* __restrict__ srcs, int E, int N) {
  const int is64 = *flag;
  const int EE = E + N;
  for (int i = blockIdx.x * blockDim.x + threadIdx.x; i < EE; i += gridDim.x * blockDim.x) {
    int s, d;
    if (i < E) {
      if (is64) { s = (int)((const long long*)ei)[i]; d = (int)((const long long*)ei)[(size_t)E + i]; }
      else      { s = ((const int*)ei)[i];            d = ((const int*)ei)[(size_t)E + i]; }
    } else { s = d = i - E; }
    int slot = atomicAdd(&cursor[d], 1);
    srcs[slot] = s;
  }
}

// --- gather-aggregate + W_conv apply -> xlocal[N,128]. One wave per node,
//     8 edges per iteration: lane = edge-slot(es=lane>>3) x head(h=lane&7). ---
__global__ __launch_bounds__(256) void k_xlocal(
    const float* __restrict__ x, const int* __restrict__ off, const int* __restrict__ srcs,
    const float* __restrict__ als, const float* __restrict__ ald,
    const float* __restrict__ Wc, const float* __restrict__ b_conv,
    float* __restrict__ xlocal, int N) {
  __shared__ float W2t[2048];     // [d][h*16+f]
  __shared__ float myx[4][128];
  __shared__ float dsh[4][8];
  for (int i = threadIdx.x; i < 2048; i += blockDim.x) {
    int h = i >> 8, d = (i >> 4) & 15, f = i & 15;
    W2t[d * 128 + h * 16 + f] = Wc[i];
  }
  __syncthreads();
  const int wid = threadIdx.x >> 6, lane = threadIdx.x & 63;
  const int es = lane >> 3, h = lane & 7;
  const int c0 = lane, c1 = lane + 64;
  const int h0 = lane >> 4, h1 = h0 + 4;
  const float bc0 = b_conv[c0], bc1 = b_conv[c1];
  const int gw = blockIdx.x * 4 + wid, nwv = gridDim.x * 4;
  for (int n = gw; n < N; n += nwv) {
    const int beg = off[n], end = off[n + 1];
    const float aldh = ald[(size_t)n * 8 + h];
    float acc[16];
#pragma unroll
    for (int d = 0; d < 16; ++d) acc[d] = 0.f;
    float den = 0.f;
    // prologue: load strip 0
    int s = srcs[min(beg + es, end - 1)];
    float av = als[(size_t)s * 8 + h];
    const float4* xr = (const float4*)(x + (size_t)s * 16);
    float4 v0 = xr[0], v1 = xr[1], v2 = xr[2], v3 = xr[3];
    for (int base = beg; base < end; base += 8) {
      // prefetch next strip (clamped; always-safe addresses)
      int sn = srcs[min(base + 8 + es, end - 1)];
      float avn = als[(size_t)sn * 8 + h];
      const float4* xrn = (const float4*)(x + (size_t)sn * 16);
      float4 n0 = xrn[0], n1 = xrn[1], n2 = xrn[2], n3 = xrn[3];
      // compute current strip
      float e = av + aldh;
      float w = ((base + es) < end) ? __expf(e >= 0.f ? e : 0.2f * e) : 0.f;
      den += w;
      acc[0] += w * v0.x;  acc[1] += w * v0.y;  acc[2] += w * v0.z;  acc[3] += w * v0.w;
      acc[4] += w * v1.x;  acc[5] += w * v1.y;  acc[6] += w * v1.z;  acc[7] += w * v1.w;
      acc[8] += w * v2.x;  acc[9] += w * v2.y;  acc[10] += w * v2.z; acc[11] += w * v2.w;
      acc[12] += w * v3.x; acc[13] += w * v3.y; acc[14] += w * v3.z; acc[15] += w * v3.w;
      s = sn; av = avn; v0 = n0; v1 = n1; v2 = n2; v3 = n3;
    }
    // reduce across the 8 edge-slots (lanes h, h+8, ..., h+56)
#pragma unroll
    for (int m = 8; m < 64; m <<= 1) {
#pragma unroll
      for (int d = 0; d < 16; ++d) acc[d] += __shfl_xor(acc[d], m, 64);
      den += __shfl_xor(den, m, 64);
    }
    if (es == 0) {
#pragma unroll
      for (int d = 0; d < 16; ++d) myx[wid][h * 16 + d] = acc[d];
      dsh[wid][h] = den;
    }
    // x_local[c] = (W_h . acc_h)/den_h + b_conv[c]
    const float rd0 = 1.f / dsh[wid][h0];
    const float rd1 = 1.f / dsh[wid][h1];
    float xl0 = 0.f, xl1 = 0.f;
#pragma unroll
    for (int d = 0; d < 16; ++d) {
      xl0 += myx[wid][h0 * 16 + d] * W2t[d * 128 + c0];
      xl1 += myx[wid][h1 * 16 + d] * W2t[d * 128 + c1];
    }
    xlocal[(size_t)n * 128 + c0] = xl0 * rd0 + bc0;
    xlocal[(size_t)n * 128 + c1] = xl1 * rd1 + bc1;
  }
}

// --- dense chain via MFMA. One wave per 16-node tile. fc_W^T pre-swizzled bf16
//     frags in LDS; x split bf16 hi/lo (2 MFMA per op). ---
__global__ __launch_bounds__(256) void k_dense2(
    float* __restrict__ xlocal,   // in-place: rows read then overwritten
    const float* __restrict__ fcW, const float* __restrict__ fcb,
    const float* __restrict__ lng, const float* __restrict__ lnb,
    float* __restrict__ colsum, int N) {
  __shared__ bf16x8 Bf[2048];     // 32 KB: B[k][c]=fcW[c][k] in frag order [t][q][lane]
  __shared__ float xs[4][2112];   // per-wave 16x132 f32 stage (pad kills A-read conflicts)
  for (int idx = threadIdx.x; idx < 2048; idx += 256) {
    int tq = idx >> 6, l = idx & 63;
    int t = tq >> 2, q = tq & 3;
    int col = (l & 15) + t * 16;
    int kb = q * 32 + (l >> 4) * 8;
    const float* wr = fcW + col * 128 + kb;
    bf16x8 v;
#pragma unroll
    for (int i = 0; i < 8; ++i) v[i] = bf16t(wr[i]);
    Bf[idx] = v;
  }
  __syncthreads();
  const int wid = threadIdx.x >> 6, lane = threadIdx.x & 63;
  float* X = xs[wid];
  const int lg = lane >> 4;       // row-group (C) / k-group (A,B)
  const int lc = lane & 15;       // col-in-tile (C,B) / row (A)
  float fb[8], g[8], bb[8];
#pragma unroll
  for (int t = 0; t < 8; ++t) {
    int c = lc + t * 16;
    fb[t] = fcb[c]; g[t] = lng[c]; bb[t] = lnb[c];
  }
  float cs[8];
#pragma unroll
  for (int t = 0; t < 8; ++t) cs[t] = 0.f;
  const int ntiles = (N + 15) >> 4;
  const int srow = lane >> 2, sseg = lane & 3;
  for (int tile = blockIdx.x * 4 + wid; tile < ntiles; tile += gridDim.x * 4) {
    const int nb = tile * 16;
    // stage 16x128 tile of xlocal into LDS
#pragma unroll
    for (int j = 0; j < 8; ++j) {
      int n = min(nb + srow, N - 1);
      float4 v = *(const float4*)(xlocal + (size_t)n * 128 + (sseg + 4 * j) * 4);
      *(float4*)(X + srow * 132 + (sseg + 4 * j) * 4) = v;
    }
    // A fragments (hi/lo split), GEMM1
    bf16x8 Ah[4], Al[4];
#pragma unroll
    for (int q = 0; q < 4; ++q) {
      const float* p = X + lc * 132 + q * 32 + lg * 8;
      float a[8];
      *(float4*)(a) = *(const float4*)(p);
      *(float4*)(a + 4) = *(const float4*)(p + 4);
#pragma unroll
      for (int i = 0; i < 8; ++i) {
        unsigned u = __float_as_uint(a[i]);
        Ah[q][i] = (short)(u >> 16);
        Al[q][i] = bf16t(a[i] - __uint_as_float(u & 0xFFFF0000u));
      }
    }
    f32x4 acc[8];
#pragma unroll
    for (int t = 0; t < 8; ++t) acc[t] = (f32x4){0.f, 0.f, 0.f, 0.f};
#pragma unroll
    for (int t = 0; t < 8; ++t)
#pragma unroll
      for (int q = 0; q < 4; ++q) {
        bf16x8 b = Bf[(t * 4 + q) * 64 + lane];
        acc[t] = __builtin_amdgcn_mfma_f32_16x16x32_bf16(Ah[q], b, acc[t], 0, 0, 0);
        acc[t] = __builtin_amdgcn_mfma_f32_16x16x32_bf16(Al[q], b, acc[t], 0, 0, 0);
      }
    // softmax over 128 cols per node-row; xl2 = lrelu(x*att, 0.2); write back to LDS
    float l1[8][4];
#pragma unroll
    for (int t = 0; t < 8; ++t)
#pragma unroll
      for (int r = 0; r < 4; ++r) {
        float z = acc[t][r] + fb[t];
        l1[t][r] = fmaxf(z, 0.01f * z);
      }
#pragma unroll
    for (int r = 0; r < 4; ++r) {
      float m = l1[0][r];
#pragma unroll
      for (int t = 1; t < 8; ++t) m = fmaxf(m, l1[t][r]);
#pragma unroll
      for (int msk = 1; msk < 16; msk <<= 1) m = fmaxf(m, __shfl_xor(m, msk, 64));
      float s = 0.f;
#pragma unroll
      for (int t = 0; t < 8; ++t) { l1[t][r] = __expf(l1[t][r] - m); s += l1[t][r]; }
#pragma unroll
      for (int msk = 1; msk < 16; msk <<= 1) s += __shfl_xor(s, msk, 64);
      float sinv = 1.f / s;
      const int row = lg * 4 + r;
#pragma unroll
      for (int t = 0; t < 8; ++t) {
        float xv = X[row * 132 + lc + 16 * t];
        float y = xv * (l1[t][r] * sinv);
        l1[t][r] = fmaxf(y, 0.2f * y);
      }
    }
#pragma unroll
    for (int t = 0; t < 8; ++t)
#pragma unroll
      for (int r = 0; r < 4; ++r)
        X[(lg * 4 + r) * 132 + lc + 16 * t] = l1[t][r];
    // GEMM2 on xl2
#pragma unroll
    for (int q = 0; q < 4; ++q) {
      const float* p = X + lc * 132 + q * 32 + lg * 8;
      float a[8];
      *(float4*)(a) = *(const float4*)(p);
      *(float4*)(a + 4) = *(const float4*)(p + 4);
#pragma unroll
      for (int i = 0; i < 8; ++i) {
        unsigned u = __float_as_uint(a[i]);
        Ah[q][i] = (short)(u >> 16);
        Al[q][i] = bf16t(a[i] - __uint_as_float(u & 0xFFFF0000u));
      }
    }
#pragma unroll
    for (int t = 0; t < 8; ++t) acc[t] = (f32x4){0.f, 0.f, 0.f, 0.f};
#pragma unroll
    for (int t = 0; t < 8; ++t)
#pragma unroll
      for (int q = 0; q < 4; ++q) {
        bf16x8 b = Bf[(t * 4 + q) * 64 + lane];
        acc[t] = __builtin_amdgcn_mfma_f32_16x16x32_bf16(Ah[q], b, acc[t], 0, 0, 0);
        acc[t] = __builtin_amdgcn_mfma_f32_16x16x32_bf16(Al[q], b, acc[t], 0, 0, 0);
      }
    // LayerNorm + L2 normalize + store
#pragma unroll
    for (int r = 0; r < 4; ++r) {
      float z[8];
      float s = 0.f;
#pragma unroll
      for (int t = 0; t < 8; ++t) { z[t] = acc[t][r] + fb[t]; s += z[t]; }
#pragma unroll
      for (int msk = 1; msk < 16; msk <<= 1) s += __shfl_xor(s, msk, 64);
      const float mu = s * (1.f / 128.f);
      float v = 0.f;
#pragma unroll
      for (int t = 0; t < 8; ++t) { z[t] -= mu; v += z[t] * z[t]; }
#pragma unroll
      for (int msk = 1; msk < 16; msk <<= 1) v += __shfl_xor(v, msk, 64);
      const float rstd = rsqrtf(v * (1.f / 128.f) + 1e-5f);
      float q2 = 0.f;
#pragma unroll
      for (int t = 0; t < 8; ++t) { z[t] = z[t] * rstd * g[t] + bb[t]; q2 += z[t] * z[t]; }
#pragma unroll
      for (int msk = 1; msk < 16; msk <<= 1) q2 += __shfl_xor(q2, msk, 64);
      const float rinv = 1.f / fmaxf(sqrtf(q2), 1e-12f);
      const int n = nb + lg * 4 + r;
      if (n < N) {
#pragma unroll
        for (int t = 0; t < 8; ++t) {
          float o = z[t] * rinv;
          xlocal[(size_t)n * 128 + lc + 16 * t] = o;
          cs[t] += o;
        }
      }
    }
  }
#pragma unroll
  for (int t = 0; t < 8; ++t) {
    cs[t] += __shfl_xor(cs[t], 16, 64);
    cs[t] += __shfl_xor(cs[t], 32, 64);
    if (lg == 0) atomicAdd(colsum + lc + 16 * t, cs[t]);
  }
}

// --- global attention vector ga[128] ---
__global__ void k_gatt(const float* __restrict__ colsum, const float* __restrict__ gW,
                       const float* __restrict__ gb, float* __restrict__ ga, int N) {
  __shared__ float xg[128], r[128];
  int t = threadIdx.x;
  xg[t] = colsum[t] / (float)N;
  __syncthreads();
  float acc = gb[t];
  for (int k = 0; k < 128; ++k) acc += xg[k] * gW[t * 128 + k];
  acc = fmaxf(acc, 0.f);
  r[t] = acc;
  __syncthreads();
  float m = -1e30f;
  for (int k = 0; k < 128; ++k) m = fmaxf(m, r[k]);
  float s = 0.f;
  for (int k = 0; k < 128; ++k) s += __expf(r[k] - m);
  ga[t] = __expf(acc - m) / s;
}

// --- out *= ga (broadcast over rows) ---
__global__ void k_scale(float* __restrict__ out, const float* __restrict__ ga, int total4) {
  float4* o4 = (float4*)out;
  const float4* g4 = (const float4*)ga;
  for (int i = blockIdx.x * blockDim.x + threadIdx.x; i < total4; i += gridDim.x * blockDim.x) {
    float4 v = o4[i];
    float4 g = g4[i & 31];
    v.x *= g.x; v.y *= g.y; v.z *= g.z; v.w *= g.w;
    o4[i] = v;
  }
}

extern "C" void kernel_launch(void* const* d_in, const int* in_sizes, int n_in,
                              void* d_out, int out_size, void* d_ws, size_t ws_size,
                              hipStream_t stream) {
  const float* x    = (const float*)d_in[0];
  const void*  ei   = d_in[1];
  const float* Wc   = (const float*)d_in[2];
  const float* asrc = (const float*)d_in[3];
  const float* adst = (const float*)d_in[4];
  const float* bcv  = (const float*)d_in[5];
  const float* fcW  = (const float*)d_in[6];
  const float* fcb  = (const float*)d_in[7];
  const float* lng  = (const float*)d_in[8];
  const float* lnb  = (const float*)d_in[9];
  const float* gW   = (const float*)d_in[10];
  const float* gb   = (const float*)d_in[11];
  const int N = in_sizes[0] / 16;
  const int E = in_sizes[1] / 2;
  const int EE = E + N;

  float* als    = (float*)d_ws;                 // [N,8]
  float* ald    = als + (size_t)N * 8;          // [N,8]
  float* colsum = ald + (size_t)N * 8;          // [128]
  float* ga     = colsum + 128;                 // [128]
  int*   flag   = (int*)(ga + 128);             // [1]
  int*   cnt    = flag + 1;                     // [N]
  int*   off    = cnt + N;                      // [N+1]
  int*   cursor = off + N + 1;                  // [N]
  int*   srcs   = cursor + N;                   // [E+N]
  float* out    = (float*)d_out;                // doubles as xlocal

  hipMemsetAsync(colsum, 0, 128 * sizeof(float), stream);
  k_detect<<<1, 256, 0, stream>>>(ei, N, flag);
  k_init<<<128, 256, 0, stream>>>(cnt, N);
  k_alpha<<<512, 256, 0, stream>>>(x, Wc, asrc, adst, als, ald, N);
  k_count<<<1024, 256, 0, stream>>>(ei, flag, cnt, E);
  k_scan<<<1, 1024, 0, stream>>>(cnt, off, cursor, N, EE);
  k_fill<<<1024, 256, 0, stream>>>(ei, flag, cursor, srcs, E, N);
  k_xlocal<<<2048, 256, 0, stream>>>(x, off, srcs, als, ald, Wc, bcv, out, N);
  k_dense2<<<512, 256, 0, stream>>>(out, fcW, fcb, lng, lnb, colsum, N);
  k_gatt<<<1, 128, 0, stream>>>(colsum, gW, gb, ga, N);
  k_scale<<<2048, 256, 0, stream>>>(out, ga, N * 32);
}